// Round 1
// baseline (1331.876 us; speedup 1.0000x reference)
//
#include <hip/hip_runtime.h>
#include <math.h>

#define NNODES 20000
#define NEDGES 320000
#define NGRAPHS 200
#define K1 36
#define K2 26

struct WPtrs { const float* w[6]; };

__device__ __forceinline__ float sigf(float v) { return 1.0f / (1.0f + expf(-v)); }
__device__ __forceinline__ float eluf(float v) { return v > 0.0f ? v : expm1f(v); }

// ---------------------------------------------------------------------------
// Generic fused GEMM: out[:, chunk*128+half*64 : +64] = act(A[M,128] @ Wc[128,64])
// grid.x = ceil(M/64), grid.y = nchunks*2. 64x64 output tile per workgroup.
// ---------------------------------------------------------------------------
__global__ __launch_bounds__(256) void gemm128_kernel(
    const float* __restrict__ A, WPtrs wp, float* __restrict__ out,
    int out_stride, int act)
{
    __shared__ float4 Wl[2048];   // [k][f4]: k*16 + fq   (128 x 64 floats)
    __shared__ float4 Al[2048];   // [n][k4]: n*32 + k4   (64 x 128 floats)

    const int half  = blockIdx.y & 1;
    const int chunk = blockIdx.y >> 1;
    const float4* W4 = (const float4*)(wp.w[chunk] + half * 64);

    for (int idx = threadIdx.x; idx < 2048; idx += 256) {
        int k = idx >> 4, fq = idx & 15;
        Wl[idx] = W4[k * 32 + fq];           // row stride of W is 128 floats = 32 f4
    }
    const int m0 = blockIdx.x * 64;
    const float4* A4 = (const float4*)A;
    for (int idx = threadIdx.x; idx < 2048; idx += 256) {
        int r = idx >> 5, k4 = idx & 31;
        int row = m0 + r;
        Al[idx] = (row < NNODES) ? A4[(size_t)row * 32 + k4] : make_float4(0.f, 0.f, 0.f, 0.f);
    }
    __syncthreads();

    const int fg = threadIdx.x & 15;   // feature group: f' = fg*4
    const int ng = threadIdx.x >> 4;   // node group: n = ng*4 + j

    float acc[4][4] = {};
    #pragma unroll 4
    for (int k4 = 0; k4 < 32; ++k4) {
        float4 a[4], w[4];
        #pragma unroll
        for (int j = 0; j < 4; ++j) a[j] = Al[(ng * 4 + j) * 32 + k4];
        #pragma unroll
        for (int q = 0; q < 4; ++q) w[q] = Wl[(k4 * 4 + q) * 16 + fg];
        #pragma unroll
        for (int j = 0; j < 4; ++j) {
            const float* ap = (const float*)&a[j];
            #pragma unroll
            for (int q = 0; q < 4; ++q) {
                const float* wq = (const float*)&w[q];
                #pragma unroll
                for (int jj = 0; jj < 4; ++jj)
                    acc[j][jj] = fmaf(ap[q], wq[jj], acc[j][jj]);
            }
        }
    }

    const int coff = chunk * 128 + half * 64 + fg * 4;
    #pragma unroll
    for (int j = 0; j < 4; ++j) {
        int row = m0 + ng * 4 + j;
        if (row < NNODES) {
            float4 v; float* vp = (float*)&v;
            #pragma unroll
            for (int jj = 0; jj < 4; ++jj) {
                float t = acc[j][jj];
                vp[jj] = act ? sigf(t) : t;
            }
            *(float4*)(out + (size_t)row * out_stride + coff) = v;
        }
    }
}

// ---------------------------------------------------------------------------
// Edge kernel: z = sigmoid(g)*elu(m)*(cs@W1v + (pw@W2v)*sigmoid(pw@W2vg))
// g/m reconstructed from gathered node-level products P[n][6][128].
// 256 threads = 2 edges x 128 features, 64 edges per block.
// ---------------------------------------------------------------------------
__global__ __launch_bounds__(256) void edge_kernel(
    const float* __restrict__ P,
    const int* __restrict__ esrc, const int* __restrict__ etgt,
    const float* __restrict__ dist,
    const float* __restrict__ cs, const float* __restrict__ pw,
    const float* __restrict__ W1v, const float* __restrict__ W2v,
    const float* __restrict__ W2vg,
    float* __restrict__ x)
{
    const int f    = threadIdx.x & 127;
    const int esub = threadIdx.x >> 7;

    // weight columns for this feature, held in registers for the whole block
    float w1[K1], w2[K2], w2g[K2];
    #pragma unroll
    for (int k = 0; k < K1; ++k) w1[k]  = W1v[k * 128 + f];
    #pragma unroll
    for (int k = 0; k < K2; ++k) w2[k]  = W2v[k * 128 + f];
    #pragma unroll
    for (int k = 0; k < K2; ++k) w2g[k] = W2vg[k * 128 + f];

    const int ebase = blockIdx.x * 64 + esub;
    for (int it = 0; it < 32; ++it) {
        const int e = __builtin_amdgcn_readfirstlane(ebase + it * 2);  // wave-uniform
        const int s = esrc[e];
        const int t = etgt[e];
        const float invd = 1.0f / dist[e];

        const float* csr = cs + (size_t)e * K1;
        const float* pwr = pw + (size_t)e * K2;
        float z1 = 0.f, za = 0.f, zb = 0.f;
        #pragma unroll
        for (int k = 0; k < K1; ++k) z1 = fmaf(csr[k], w1[k], z1);
        #pragma unroll
        for (int k = 0; k < K2; ++k) {
            float p = pwr[k];
            za = fmaf(p, w2[k],  za);
            zb = fmaf(p, w2g[k], zb);
        }

        const float* Ps = P + (size_t)s * 768;
        const float* Pt = P + (size_t)t * 768;
        float g = Ps[f]       + Pt[128 + f] + (Pt[256 + f] - Ps[256 + f]) * invd;
        float m = Ps[384 + f] + Pt[512 + f] + (Pt[640 + f] - Ps[640 + f]) * invd;

        float z = sigf(g) * eluf(m) * (z1 + za * sigf(zb));
        atomicAdd(x + (size_t)s * 128 + f, z);
    }
}

// ---------------------------------------------------------------------------
// Pool + psi elementwise: T[n][3][128] = [x@Wp1, x@Wp2, x@Wpsi]
// pools[g] += elu(T0)*T1 ; xout = elu(T2)
// ---------------------------------------------------------------------------
__global__ __launch_bounds__(256) void pool_psi_kernel(
    const float* __restrict__ T, const int* __restrict__ gidx,
    float* __restrict__ pools, float* __restrict__ xout)
{
    int idx = blockIdx.x * 256 + threadIdx.x;
    int n = idx >> 7, f = idx & 127;
    float h1 = eluf(T[(size_t)n * 384 + f]);
    float h2 = T[(size_t)n * 384 + 128 + f];
    atomicAdd(pools + (size_t)gidx[n] * 128 + f, h1 * h2);
    xout[(size_t)n * 128 + f] = eluf(T[(size_t)n * 384 + 256 + f]);
}

// ---------------------------------------------------------------------------
// Final head: per graph: elu(@Wlr1[128,64]) -> elu(@Wlr2[64,42]) -> @Wlr3[42,1]
// ---------------------------------------------------------------------------
__global__ __launch_bounds__(64) void final_kernel(
    const float* __restrict__ pools,
    const float* __restrict__ Wlr1, const float* __restrict__ Wlr2,
    const float* __restrict__ Wlr3, float* __restrict__ out)
{
    __shared__ float h1[64];
    __shared__ float h2[42];
    const int g = blockIdx.x;
    const int f = threadIdx.x;

    float a = 0.f;
    #pragma unroll 8
    for (int k = 0; k < 128; ++k) a = fmaf(pools[(size_t)g * 128 + k], Wlr1[k * 64 + f], a);
    h1[f] = eluf(a);
    __syncthreads();
    if (f < 42) {
        float b = 0.f;
        #pragma unroll
        for (int k = 0; k < 64; ++k) b = fmaf(h1[k], Wlr2[k * 42 + f], b);
        h2[f] = eluf(b);
    }
    __syncthreads();
    if (f == 0) {
        float c = 0.f;
        #pragma unroll
        for (int k = 0; k < 42; ++k) c = fmaf(h2[k], Wlr3[k], c);
        out[g] = c;
    }
}

__global__ void zero_kernel(float* p, int n)
{
    int i = blockIdx.x * 256 + threadIdx.x;
    if (i < n) p[i] = 0.f;
}

extern "C" void kernel_launch(void* const* d_in, const int* in_sizes, int n_in,
                              void* d_out, int out_size, void* d_ws, size_t ws_size,
                              hipStream_t stream)
{
    const float* nodes = (const float*)d_in[0];
    const int*   esrc  = (const int*)d_in[1];
    const int*   etgt  = (const int*)d_in[2];
    const float* dist  = (const float*)d_in[3];
    const int*   gidx  = (const int*)d_in[4];
    // d_in[5] = node_counts : unused (division discarded in the source)
    const float* cs    = (const float*)d_in[6];
    const float* pw    = (const float*)d_in[7];
    const float* W_emb = (const float*)d_in[8];
    const float* Wg    = (const float*)d_in[9];
    const float* Wm    = (const float*)d_in[10];
    const float* W1v   = (const float*)d_in[11];
    const float* W2v   = (const float*)d_in[12];
    const float* W2vg  = (const float*)d_in[13];
    const float* Wp1   = (const float*)d_in[14];
    const float* Wp2   = (const float*)d_in[15];
    const float* Wpsi  = (const float*)d_in[16];
    const float* Wlr1  = (const float*)d_in[17];
    const float* Wlr2  = (const float*)d_in[18];
    const float* Wlr3  = (const float*)d_in[19];
    float* outp = (float*)d_out;

    // workspace layout (floats): xA | xB | P(=T overlay) | pools
    float* xA    = (float*)d_ws;
    float* xB    = xA + (size_t)NNODES * 128;
    float* P     = xB + (size_t)NNODES * 128;
    float* pools = P + (size_t)NNODES * 768;   // total ~82 MB

    zero_kernel<<<100, 256, 0, stream>>>(pools, NGRAPHS * 128);

    // x = sigmoid(nodes @ W_emb)
    {
        WPtrs wp{}; wp.w[0] = W_emb;
        gemm128_kernel<<<dim3(313, 2), 256, 0, stream>>>(nodes, wp, xA, 128, 1);
    }

    float* xc = xA;
    float* xn = xB;
    for (int i = 0; i < 3; ++i) {
        // P = x @ [Wg0,Wg1,Wg2,Wm0,Wm1,Wm2]  (each 128x128, contiguous in Wg/Wm)
        WPtrs wp{};
        const float* Wgi = Wg + (size_t)i * 49152;
        const float* Wmi = Wm + (size_t)i * 49152;
        wp.w[0] = Wgi;          wp.w[1] = Wgi + 16384;  wp.w[2] = Wgi + 32768;
        wp.w[3] = Wmi;          wp.w[4] = Wmi + 16384;  wp.w[5] = Wmi + 32768;
        gemm128_kernel<<<dim3(313, 12), 256, 0, stream>>>(xc, wp, P, 768, 0);

        // gather/combine/scatter over edges (updates xc in place; reads only P)
        edge_kernel<<<5000, 256, 0, stream>>>(P, esrc, etgt, dist, cs, pw,
            W1v + (size_t)i * (K1 * 128),
            W2v + (size_t)i * (K2 * 128),
            W2vg + (size_t)i * (K2 * 128), xc);

        // T = x @ [Wp1, Wp2, Wpsi]  (reuse P buffer)
        WPtrs wq{};
        wq.w[0] = Wp1 + (size_t)i * 16384;
        wq.w[1] = Wp2 + (size_t)i * 16384;
        wq.w[2] = Wpsi + (size_t)i * 16384;
        gemm128_kernel<<<dim3(313, 6), 256, 0, stream>>>(xc, wq, P, 384, 0);

        // pools[g] += elu(T0)*T1 ; xn = elu(T2)
        pool_psi_kernel<<<10000, 256, 0, stream>>>(P, gidx, pools, xn);

        float* tmp = xc; xc = xn; xn = tmp;
    }

    final_kernel<<<NGRAPHS, 64, 0, stream>>>(pools, Wlr1, Wlr2, Wlr3, outp);
}

// Round 2
// 1253.291 us; speedup vs baseline: 1.0627x; 1.0627x over previous
//
#include <hip/hip_runtime.h>
#include <math.h>

#define NNODES 20000
#define NEDGES 320000
#define NGRAPHS 200
#define K1 36
#define K2 26

struct WPtrs { const float* w[6]; };

__device__ __forceinline__ float sigf(float v) { return 1.0f / (1.0f + expf(-v)); }
__device__ __forceinline__ float eluf(float v) { return v > 0.0f ? v : expm1f(v); }

// ---------------------------------------------------------------------------
// Generic fused GEMM: out[:, chunk*128+half*64 : +64] = act(A[M,128] @ Wc[128,64])
// grid.x = ceil(M/64), grid.y = nchunks*2. 64x64 output tile per workgroup.
// ---------------------------------------------------------------------------
__global__ __launch_bounds__(256) void gemm128_kernel(
    const float* __restrict__ A, WPtrs wp, float* __restrict__ out,
    int out_stride, int act)
{
    __shared__ float4 Wl[2048];   // [k][f4]: k*16 + fq   (128 x 64 floats)
    __shared__ float4 Al[2048];   // [n][k4]: n*32 + k4   (64 x 128 floats)

    const int half  = blockIdx.y & 1;
    const int chunk = blockIdx.y >> 1;
    const float4* W4 = (const float4*)(wp.w[chunk] + half * 64);

    for (int idx = threadIdx.x; idx < 2048; idx += 256) {
        int k = idx >> 4, fq = idx & 15;
        Wl[idx] = W4[k * 32 + fq];           // row stride of W is 128 floats = 32 f4
    }
    const int m0 = blockIdx.x * 64;
    const float4* A4 = (const float4*)A;
    for (int idx = threadIdx.x; idx < 2048; idx += 256) {
        int r = idx >> 5, k4 = idx & 31;
        int row = m0 + r;
        Al[idx] = (row < NNODES) ? A4[(size_t)row * 32 + k4] : make_float4(0.f, 0.f, 0.f, 0.f);
    }
    __syncthreads();

    const int fg = threadIdx.x & 15;   // feature group: f' = fg*4
    const int ng = threadIdx.x >> 4;   // node group: n = ng*4 + j

    float acc[4][4] = {};
    #pragma unroll 4
    for (int k4 = 0; k4 < 32; ++k4) {
        float4 a[4], w[4];
        #pragma unroll
        for (int j = 0; j < 4; ++j) a[j] = Al[(ng * 4 + j) * 32 + k4];
        #pragma unroll
        for (int q = 0; q < 4; ++q) w[q] = Wl[(k4 * 4 + q) * 16 + fg];
        #pragma unroll
        for (int j = 0; j < 4; ++j) {
            const float* ap = (const float*)&a[j];
            #pragma unroll
            for (int q = 0; q < 4; ++q) {
                const float* wq = (const float*)&w[q];
                #pragma unroll
                for (int jj = 0; jj < 4; ++jj)
                    acc[j][jj] = fmaf(ap[q], wq[jj], acc[j][jj]);
            }
        }
    }

    const int coff = chunk * 128 + half * 64 + fg * 4;
    #pragma unroll
    for (int j = 0; j < 4; ++j) {
        int row = m0 + ng * 4 + j;
        if (row < NNODES) {
            float4 v; float* vp = (float*)&v;
            #pragma unroll
            for (int jj = 0; jj < 4; ++jj) {
                float t = acc[j][jj];
                vp[jj] = act ? sigf(t) : t;
            }
            *(float4*)(out + (size_t)row * out_stride + coff) = v;
        }
    }
}

// ---------------------------------------------------------------------------
// Edge kernel: z = sigmoid(g)*elu(m)*(cs@W1v + (pw@W2v)*sigmoid(pw@W2vg))
// g/m reconstructed from gathered node-level products P[n][6][128].
// 256 threads = 2 edges x 128 features, 64 edges per block, 32 iterations.
// __launch_bounds__(256,2): 256-VGPR budget so the 88 weight floats stay
// resident (R1: default heuristic gave VGPR=56 -> weights reloaded from L1
// every iteration -> ~350us of redundant VMEM; this was the bottleneck).
// ---------------------------------------------------------------------------
__global__ __launch_bounds__(256, 2) void edge_kernel(
    const float* __restrict__ P,
    const int* __restrict__ esrc, const int* __restrict__ etgt,
    const float* __restrict__ dist,
    const float* __restrict__ cs, const float* __restrict__ pw,
    const float* __restrict__ W1v, const float* __restrict__ W2v,
    const float* __restrict__ W2vg,
    float* __restrict__ x)
{
    const int f    = threadIdx.x & 127;
    const int esub = threadIdx.x >> 7;

    // weight columns for this feature, resident in VGPRs for the whole block
    float w1[K1], w2[K2], w2g[K2];
    #pragma unroll
    for (int k = 0; k < K1; ++k) w1[k]  = W1v[k * 128 + f];
    #pragma unroll
    for (int k = 0; k < K2; ++k) w2[k]  = W2v[k * 128 + f];
    #pragma unroll
    for (int k = 0; k < K2; ++k) w2g[k] = W2vg[k * 128 + f];

    const int ebase = blockIdx.x * 64 + esub;

    // prefetched edge metadata (wave-uniform)
    int e  = __builtin_amdgcn_readfirstlane(ebase);
    int s  = esrc[e];
    int t  = etgt[e];
    float d = dist[e];

    for (int it = 0; it < 32; ++it) {
        // issue the 8 P-gathers for the current edge first (long-latency)
        const float* Ps = P + (size_t)s * 768;
        const float* Pt = P + (size_t)t * 768;
        float g0 = Ps[f];
        float g1 = Pt[128 + f];
        float g2t = Pt[256 + f];
        float g2s = Ps[256 + f];
        float m0 = Ps[384 + f];
        float m1 = Pt[512 + f];
        float m2t = Pt[640 + f];
        float m2s = Ps[640 + f];

        // edge-feature dot products (cs/pw rows are wave-uniform -> SMEM loads)
        const float* csr = cs + (size_t)e * K1;
        const float* pwr = pw + (size_t)e * K2;
        float z1 = 0.f, za = 0.f, zb = 0.f;
        #pragma unroll
        for (int k = 0; k < K1; ++k) z1 = fmaf(csr[k], w1[k], z1);
        #pragma unroll
        for (int k = 0; k < K2; ++k) {
            float p = pwr[k];
            za = fmaf(p, w2[k],  za);
            zb = fmaf(p, w2g[k], zb);
        }

        const float invd = 1.0f / d;
        const int scur = s;

        // prefetch next edge's metadata before the dependent math
        if (it < 31) {
            int en = __builtin_amdgcn_readfirstlane(ebase + (it + 1) * 2);
            s = esrc[en];
            t = etgt[en];
            d = dist[en];
            e = en;
        }

        float g = g0 + g1 + (g2t - g2s) * invd;
        float m = m0 + m1 + (m2t - m2s) * invd;
        float z = sigf(g) * eluf(m) * (z1 + za * sigf(zb));
        atomicAdd(x + (size_t)scur * 128 + f, z);
    }
}

// ---------------------------------------------------------------------------
// Pool + psi elementwise: T[n][3][128] = [x@Wp1, x@Wp2, x@Wpsi]
// pools[g] += elu(T0)*T1 ; xout = elu(T2)
// ---------------------------------------------------------------------------
__global__ __launch_bounds__(256) void pool_psi_kernel(
    const float* __restrict__ T, const int* __restrict__ gidx,
    float* __restrict__ pools, float* __restrict__ xout)
{
    int idx = blockIdx.x * 256 + threadIdx.x;
    int n = idx >> 7, f = idx & 127;
    float h1 = eluf(T[(size_t)n * 384 + f]);
    float h2 = T[(size_t)n * 384 + 128 + f];
    atomicAdd(pools + (size_t)gidx[n] * 128 + f, h1 * h2);
    xout[(size_t)n * 128 + f] = eluf(T[(size_t)n * 384 + 256 + f]);
}

// ---------------------------------------------------------------------------
// Final head: per graph: elu(@Wlr1[128,64]) -> elu(@Wlr2[64,42]) -> @Wlr3[42,1]
// ---------------------------------------------------------------------------
__global__ __launch_bounds__(64) void final_kernel(
    const float* __restrict__ pools,
    const float* __restrict__ Wlr1, const float* __restrict__ Wlr2,
    const float* __restrict__ Wlr3, float* __restrict__ out)
{
    __shared__ float h1[64];
    __shared__ float h2[42];
    const int g = blockIdx.x;
    const int f = threadIdx.x;

    float a = 0.f;
    #pragma unroll 8
    for (int k = 0; k < 128; ++k) a = fmaf(pools[(size_t)g * 128 + k], Wlr1[k * 64 + f], a);
    h1[f] = eluf(a);
    __syncthreads();
    if (f < 42) {
        float b = 0.f;
        #pragma unroll
        for (int k = 0; k < 64; ++k) b = fmaf(h1[k], Wlr2[k * 42 + f], b);
        h2[f] = eluf(b);
    }
    __syncthreads();
    if (f == 0) {
        float c = 0.f;
        #pragma unroll
        for (int k = 0; k < 42; ++k) c = fmaf(h2[k], Wlr3[k], c);
        out[g] = c;
    }
}

__global__ void zero_kernel(float* p, int n)
{
    int i = blockIdx.x * 256 + threadIdx.x;
    if (i < n) p[i] = 0.f;
}

extern "C" void kernel_launch(void* const* d_in, const int* in_sizes, int n_in,
                              void* d_out, int out_size, void* d_ws, size_t ws_size,
                              hipStream_t stream)
{
    const float* nodes = (const float*)d_in[0];
    const int*   esrc  = (const int*)d_in[1];
    const int*   etgt  = (const int*)d_in[2];
    const float* dist  = (const float*)d_in[3];
    const int*   gidx  = (const int*)d_in[4];
    // d_in[5] = node_counts : unused (division discarded in the source)
    const float* cs    = (const float*)d_in[6];
    const float* pw    = (const float*)d_in[7];
    const float* W_emb = (const float*)d_in[8];
    const float* Wg    = (const float*)d_in[9];
    const float* Wm    = (const float*)d_in[10];
    const float* W1v   = (const float*)d_in[11];
    const float* W2v   = (const float*)d_in[12];
    const float* W2vg  = (const float*)d_in[13];
    const float* Wp1   = (const float*)d_in[14];
    const float* Wp2   = (const float*)d_in[15];
    const float* Wpsi  = (const float*)d_in[16];
    const float* Wlr1  = (const float*)d_in[17];
    const float* Wlr2  = (const float*)d_in[18];
    const float* Wlr3  = (const float*)d_in[19];
    float* outp = (float*)d_out;

    // workspace layout (floats): xA | xB | P(=T overlay) | pools
    float* xA    = (float*)d_ws;
    float* xB    = xA + (size_t)NNODES * 128;
    float* P     = xB + (size_t)NNODES * 128;
    float* pools = P + (size_t)NNODES * 768;   // total ~82 MB

    zero_kernel<<<100, 256, 0, stream>>>(pools, NGRAPHS * 128);

    // x = sigmoid(nodes @ W_emb)
    {
        WPtrs wp{}; wp.w[0] = W_emb;
        gemm128_kernel<<<dim3(313, 2), 256, 0, stream>>>(nodes, wp, xA, 128, 1);
    }

    float* xc = xA;
    float* xn = xB;
    for (int i = 0; i < 3; ++i) {
        // P = x @ [Wg0,Wg1,Wg2,Wm0,Wm1,Wm2]  (each 128x128, contiguous in Wg/Wm)
        WPtrs wp{};
        const float* Wgi = Wg + (size_t)i * 49152;
        const float* Wmi = Wm + (size_t)i * 49152;
        wp.w[0] = Wgi;          wp.w[1] = Wgi + 16384;  wp.w[2] = Wgi + 32768;
        wp.w[3] = Wmi;          wp.w[4] = Wmi + 16384;  wp.w[5] = Wmi + 32768;
        gemm128_kernel<<<dim3(313, 12), 256, 0, stream>>>(xc, wp, P, 768, 0);

        // gather/combine/scatter over edges (updates xc in place; reads only P)
        edge_kernel<<<5000, 256, 0, stream>>>(P, esrc, etgt, dist, cs, pw,
            W1v + (size_t)i * (K1 * 128),
            W2v + (size_t)i * (K2 * 128),
            W2vg + (size_t)i * (K2 * 128), xc);

        // T = x @ [Wp1, Wp2, Wpsi]  (reuse P buffer)
        WPtrs wq{};
        wq.w[0] = Wp1 + (size_t)i * 16384;
        wq.w[1] = Wp2 + (size_t)i * 16384;
        wq.w[2] = Wpsi + (size_t)i * 16384;
        gemm128_kernel<<<dim3(313, 6), 256, 0, stream>>>(xc, wq, P, 384, 0);

        // pools[g] += elu(T0)*T1 ; xn = elu(T2)
        pool_psi_kernel<<<10000, 256, 0, stream>>>(P, gidx, pools, xn);

        float* tmp = xc; xc = xn; xn = tmp;
    }

    final_kernel<<<NGRAPHS, 64, 0, stream>>>(pools, Wlr1, Wlr2, Wlr3, outp);
}

// Round 3
// 1249.954 us; speedup vs baseline: 1.0655x; 1.0027x over previous
//
#include <hip/hip_runtime.h>
#include <math.h>

#define NNODES 20000
#define NEDGES 320000
#define NGRAPHS 200
#define K1 36
#define K2 26

struct WPtrs { const float* w[6]; };

__device__ __forceinline__ float sigf(float v) { return 1.0f / (1.0f + expf(-v)); }
__device__ __forceinline__ float eluf(float v) { return v > 0.0f ? v : expm1f(v); }

// ---------------------------------------------------------------------------
// Generic fused GEMM: out[:, chunk*128+half*64 : +64] = act(A[M,128] @ Wc[128,64])
// grid.x = ceil(M/64), grid.y = nchunks*2. 64x64 output tile per workgroup.
// ---------------------------------------------------------------------------
__global__ __launch_bounds__(256) void gemm128_kernel(
    const float* __restrict__ A, WPtrs wp, float* __restrict__ out,
    int out_stride, int act)
{
    __shared__ float4 Wl[2048];   // [k][f4]: k*16 + fq   (128 x 64 floats)
    __shared__ float4 Al[2048];   // [n][k4]: n*32 + k4   (64 x 128 floats)

    const int half  = blockIdx.y & 1;
    const int chunk = blockIdx.y >> 1;
    const float4* W4 = (const float4*)(wp.w[chunk] + half * 64);

    for (int idx = threadIdx.x; idx < 2048; idx += 256) {
        int k = idx >> 4, fq = idx & 15;
        Wl[idx] = W4[k * 32 + fq];           // row stride of W is 128 floats = 32 f4
    }
    const int m0 = blockIdx.x * 64;
    const float4* A4 = (const float4*)A;
    for (int idx = threadIdx.x; idx < 2048; idx += 256) {
        int r = idx >> 5, k4 = idx & 31;
        int row = m0 + r;
        Al[idx] = (row < NNODES) ? A4[(size_t)row * 32 + k4] : make_float4(0.f, 0.f, 0.f, 0.f);
    }
    __syncthreads();

    const int fg = threadIdx.x & 15;   // feature group: f' = fg*4
    const int ng = threadIdx.x >> 4;   // node group: n = ng*4 + j

    float acc[4][4] = {};
    #pragma unroll 4
    for (int k4 = 0; k4 < 32; ++k4) {
        float4 a[4], w[4];
        #pragma unroll
        for (int j = 0; j < 4; ++j) a[j] = Al[(ng * 4 + j) * 32 + k4];
        #pragma unroll
        for (int q = 0; q < 4; ++q) w[q] = Wl[(k4 * 4 + q) * 16 + fg];
        #pragma unroll
        for (int j = 0; j < 4; ++j) {
            const float* ap = (const float*)&a[j];
            #pragma unroll
            for (int q = 0; q < 4; ++q) {
                const float* wq = (const float*)&w[q];
                #pragma unroll
                for (int jj = 0; jj < 4; ++jj)
                    acc[j][jj] = fmaf(ap[q], wq[jj], acc[j][jj]);
            }
        }
    }

    const int coff = chunk * 128 + half * 64 + fg * 4;
    #pragma unroll
    for (int j = 0; j < 4; ++j) {
        int row = m0 + ng * 4 + j;
        if (row < NNODES) {
            float4 v; float* vp = (float*)&v;
            #pragma unroll
            for (int jj = 0; jj < 4; ++jj) {
                float t = acc[j][jj];
                vp[jj] = act ? sigf(t) : t;
            }
            *(float4*)(out + (size_t)row * out_stride + coff) = v;
        }
    }
}

// ---------------------------------------------------------------------------
// Edge kernel: z = sigmoid(g)*elu(m)*(cs@W1v + (pw@W2v)*sigmoid(pw@W2vg))
// g/m reconstructed from gathered node-level products P[n][6][128].
// 256 threads = 2 edges x 128 features, 64 edges per block, 32 iterations.
//
// R1: default heuristic gave VGPR=56 -> 88 weight floats reloaded from L1
//     every iteration (~810 VALU cyc/iter vs ~230 necessary).
// R2: __launch_bounds__(256,2) raised the budget but the compiler STILL
//     rematerialized (VGPR stayed 56). Fix: asm "+v" pin after the loads —
//     the value becomes an opaque asm result, rematerialization impossible.
// ---------------------------------------------------------------------------
__global__ __launch_bounds__(256, 2) void edge_kernel(
    const float* __restrict__ P,
    const int* __restrict__ esrc, const int* __restrict__ etgt,
    const float* __restrict__ dist,
    const float* __restrict__ cs, const float* __restrict__ pw,
    const float* __restrict__ W1v, const float* __restrict__ W2v,
    const float* __restrict__ W2vg,
    float* __restrict__ x)
{
    const int f    = threadIdx.x & 127;
    const int esub = threadIdx.x >> 7;

    // weight columns for this feature, pinned resident in VGPRs
    float w1[K1], w2[K2], w2g[K2];
    #pragma unroll
    for (int k = 0; k < K1; ++k) w1[k]  = W1v[k * 128 + f];
    #pragma unroll
    for (int k = 0; k < K2; ++k) w2[k]  = W2v[k * 128 + f];
    #pragma unroll
    for (int k = 0; k < K2; ++k) w2g[k] = W2vg[k * 128 + f];
    // pin: forbid rematerialization of the loads above
    #pragma unroll
    for (int k = 0; k < K1; ++k) asm volatile("" : "+v"(w1[k]));
    #pragma unroll
    for (int k = 0; k < K2; ++k) asm volatile("" : "+v"(w2[k]));
    #pragma unroll
    for (int k = 0; k < K2; ++k) asm volatile("" : "+v"(w2g[k]));

    const int ebase = blockIdx.x * 64 + esub;

    // prefetched edge metadata (wave-uniform)
    int e  = __builtin_amdgcn_readfirstlane(ebase);
    int s  = esrc[e];
    int t  = etgt[e];
    float d = dist[e];

    for (int it = 0; it < 32; ++it) {
        // issue the 8 P-gathers for the current edge first (long-latency)
        const float* Ps = P + (size_t)s * 768;
        const float* Pt = P + (size_t)t * 768;
        float g0 = Ps[f];
        float g1 = Pt[128 + f];
        float g2t = Pt[256 + f];
        float g2s = Ps[256 + f];
        float m0 = Ps[384 + f];
        float m1 = Pt[512 + f];
        float m2t = Pt[640 + f];
        float m2s = Ps[640 + f];

        // edge-feature dot products (cs/pw rows are wave-uniform -> SMEM loads)
        const float* csr = cs + (size_t)e * K1;
        const float* pwr = pw + (size_t)e * K2;
        float z1 = 0.f, za = 0.f, zb = 0.f;
        #pragma unroll
        for (int k = 0; k < K1; ++k) z1 = fmaf(csr[k], w1[k], z1);
        #pragma unroll
        for (int k = 0; k < K2; ++k) {
            float p = pwr[k];
            za = fmaf(p, w2[k],  za);
            zb = fmaf(p, w2g[k], zb);
        }

        const float invd = 1.0f / d;
        const int scur = s;

        // prefetch next edge's metadata before the dependent math
        if (it < 31) {
            int en = __builtin_amdgcn_readfirstlane(ebase + (it + 1) * 2);
            s = esrc[en];
            t = etgt[en];
            d = dist[en];
            e = en;
        }

        float g = g0 + g1 + (g2t - g2s) * invd;
        float m = m0 + m1 + (m2t - m2s) * invd;
        float z = sigf(g) * eluf(m) * (z1 + za * sigf(zb));
        atomicAdd(x + (size_t)scur * 128 + f, z);
    }
}

// ---------------------------------------------------------------------------
// Pool + psi elementwise: T[n][3][128] = [x@Wp1, x@Wp2, x@Wpsi]
// pools[g] += elu(T0)*T1 ; xout = elu(T2)
// ---------------------------------------------------------------------------
__global__ __launch_bounds__(256) void pool_psi_kernel(
    const float* __restrict__ T, const int* __restrict__ gidx,
    float* __restrict__ pools, float* __restrict__ xout)
{
    int idx = blockIdx.x * 256 + threadIdx.x;
    int n = idx >> 7, f = idx & 127;
    float h1 = eluf(T[(size_t)n * 384 + f]);
    float h2 = T[(size_t)n * 384 + 128 + f];
    atomicAdd(pools + (size_t)gidx[n] * 128 + f, h1 * h2);
    xout[(size_t)n * 128 + f] = eluf(T[(size_t)n * 384 + 256 + f]);
}

// ---------------------------------------------------------------------------
// Final head: per graph: elu(@Wlr1[128,64]) -> elu(@Wlr2[64,42]) -> @Wlr3[42,1]
// ---------------------------------------------------------------------------
__global__ __launch_bounds__(64) void final_kernel(
    const float* __restrict__ pools,
    const float* __restrict__ Wlr1, const float* __restrict__ Wlr2,
    const float* __restrict__ Wlr3, float* __restrict__ out)
{
    __shared__ float h1[64];
    __shared__ float h2[42];
    const int g = blockIdx.x;
    const int f = threadIdx.x;

    float a = 0.f;
    #pragma unroll 8
    for (int k = 0; k < 128; ++k) a = fmaf(pools[(size_t)g * 128 + k], Wlr1[k * 64 + f], a);
    h1[f] = eluf(a);
    __syncthreads();
    if (f < 42) {
        float b = 0.f;
        #pragma unroll
        for (int k = 0; k < 64; ++k) b = fmaf(h1[k], Wlr2[k * 42 + f], b);
        h2[f] = eluf(b);
    }
    __syncthreads();
    if (f == 0) {
        float c = 0.f;
        #pragma unroll
        for (int k = 0; k < 42; ++k) c = fmaf(h2[k], Wlr3[k], c);
        out[g] = c;
    }
}

__global__ void zero_kernel(float* p, int n)
{
    int i = blockIdx.x * 256 + threadIdx.x;
    if (i < n) p[i] = 0.f;
}

extern "C" void kernel_launch(void* const* d_in, const int* in_sizes, int n_in,
                              void* d_out, int out_size, void* d_ws, size_t ws_size,
                              hipStream_t stream)
{
    const float* nodes = (const float*)d_in[0];
    const int*   esrc  = (const int*)d_in[1];
    const int*   etgt  = (const int*)d_in[2];
    const float* dist  = (const float*)d_in[3];
    const int*   gidx  = (const int*)d_in[4];
    // d_in[5] = node_counts : unused (division discarded in the source)
    const float* cs    = (const float*)d_in[6];
    const float* pw    = (const float*)d_in[7];
    const float* W_emb = (const float*)d_in[8];
    const float* Wg    = (const float*)d_in[9];
    const float* Wm    = (const float*)d_in[10];
    const float* W1v   = (const float*)d_in[11];
    const float* W2v   = (const float*)d_in[12];
    const float* W2vg  = (const float*)d_in[13];
    const float* Wp1   = (const float*)d_in[14];
    const float* Wp2   = (const float*)d_in[15];
    const float* Wpsi  = (const float*)d_in[16];
    const float* Wlr1  = (const float*)d_in[17];
    const float* Wlr2  = (const float*)d_in[18];
    const float* Wlr3  = (const float*)d_in[19];
    float* outp = (float*)d_out;

    // workspace layout (floats): xA | xB | P(=T overlay) | pools
    float* xA    = (float*)d_ws;
    float* xB    = xA + (size_t)NNODES * 128;
    float* P     = xB + (size_t)NNODES * 128;
    float* pools = P + (size_t)NNODES * 768;   // total ~82 MB

    zero_kernel<<<100, 256, 0, stream>>>(pools, NGRAPHS * 128);

    // x = sigmoid(nodes @ W_emb)
    {
        WPtrs wp{}; wp.w[0] = W_emb;
        gemm128_kernel<<<dim3(313, 2), 256, 0, stream>>>(nodes, wp, xA, 128, 1);
    }

    float* xc = xA;
    float* xn = xB;
    for (int i = 0; i < 3; ++i) {
        // P = x @ [Wg0,Wg1,Wg2,Wm0,Wm1,Wm2]  (each 128x128, contiguous in Wg/Wm)
        WPtrs wp{};
        const float* Wgi = Wg + (size_t)i * 49152;
        const float* Wmi = Wm + (size_t)i * 49152;
        wp.w[0] = Wgi;          wp.w[1] = Wgi + 16384;  wp.w[2] = Wgi + 32768;
        wp.w[3] = Wmi;          wp.w[4] = Wmi + 16384;  wp.w[5] = Wmi + 32768;
        gemm128_kernel<<<dim3(313, 12), 256, 0, stream>>>(xc, wp, P, 768, 0);

        // gather/combine/scatter over edges (updates xc in place; reads only P)
        edge_kernel<<<5000, 256, 0, stream>>>(P, esrc, etgt, dist, cs, pw,
            W1v + (size_t)i * (K1 * 128),
            W2v + (size_t)i * (K2 * 128),
            W2vg + (size_t)i * (K2 * 128), xc);

        // T = x @ [Wp1, Wp2, Wpsi]  (reuse P buffer)
        WPtrs wq{};
        wq.w[0] = Wp1 + (size_t)i * 16384;
        wq.w[1] = Wp2 + (size_t)i * 16384;
        wq.w[2] = Wpsi + (size_t)i * 16384;
        gemm128_kernel<<<dim3(313, 6), 256, 0, stream>>>(xc, wq, P, 384, 0);

        // pools[g] += elu(T0)*T1 ; xn = elu(T2)
        pool_psi_kernel<<<10000, 256, 0, stream>>>(P, gidx, pools, xn);

        float* tmp = xc; xc = xn; xn = tmp;
    }

    final_kernel<<<NGRAPHS, 64, 0, stream>>>(pools, Wlr1, Wlr2, Wlr3, outp);
}